// Round 6
// baseline (172.823 us; speedup 1.0000x reference)
//
#include <hip/hip_runtime.h>
#include <stdint.h>

#define TPB 256
#define BB  128
#define SS  512
#define LLW 20
#define NN  (BB * SS * LLW)   // 1,310,720

// lens -> LDS, inclusive prefix of per-batch viable counts
// (count(b) = L*len_b - L(L-1)/2, len>=L guaranteed), max(lens).
static __device__ __forceinline__ void preamble(const int* __restrict__ lens,
                                                int* shC, int* shM, int* shLen,
                                                int t) {
  int len0 = (t < BB) ? lens[t] : 0;
  shLen[t] = len0;
  shC[t] = (t < BB) ? (LLW * len0 - (LLW * (LLW - 1)) / 2) : 0;
  shM[t] = len0;
  for (int off = 1; off < TPB; off <<= 1) {
    __syncthreads();
    int aC = shC[t]; int bC = (t >= off) ? shC[t - off] : 0;
    int aM = shM[t]; int bM = shM[t ^ off];
    __syncthreads();
    shC[t] = aC + bC;
    shM[t] = (aM > bM) ? aM : bM;
  }
  __syncthreads();
}

// Invert compacted index k -> (b, s, j). k >= K gives pad (0,0,0).
static __device__ __forceinline__ void invert(int k, const int* shC,
                                              const int* shLen, int K,
                                              int* pb, int* ps, int* pj) {
  int b = 0, s = 0, j = 0;
  if (k < K) {
    int lo = 0, hi = BB - 1;
    while (lo < hi) {            // smallest b with inclusive count > k
      int mid = (lo + hi) >> 1;
      if (shC[mid] > k) hi = mid; else lo = mid + 1;
    }
    b = lo;
    int base = (b == 0) ? 0 : shC[b - 1];
    int m    = k - base;
    int lenb = shLen[b];
    int full = LLW * (lenb - LLW + 1);   // rows with all L spans viable
    if (m < full) {
      s = m / LLW;
      j = m - s * LLW;
    } else {                             // triangular tail; row s has len_b - s spans
      int Cb = shC[b] - base;
      int tt = Cb - m;                   // in (r(r-1)/2, r(r+1)/2], r = lenb - s
      float rf = (sqrtf(8.0f * (float)tt + 1.0f) - 1.0f) * 0.5f;
      int r = (int)(rf + 0.5f);
      if (r * (r + 1) / 2 < tt) r++;
      if (r > 1 && r * (r - 1) / 2 >= tt) r--;
      s = lenb - r;
      j = r * (r + 1) / 2 - tt;
    }
  }
  *pb = b; *ps = s; *pj = j;
}

// d_out is FLOAT32 (reference outputs are f32/int/bool; harness bf16-quantizes
// only for comparison). Standard return-order layout, offsets in units of NN:
//   0 viable | 1 batch | 2 starts | 3 ends | 4 lengths | 5..24 units
//   25 p_weights | 26 start_cand | 27 end_cand | 28 len_cand
__global__ __launch_bounds__(TPB) void span_full(
    const int* __restrict__ seqs,    // [B*S] int32
    const int* __restrict__ lens,    // [B] int32
    const float* __restrict__ pw,    // [B*S*L] f32
    float* __restrict__ out) {
  __shared__ int shC[TPB], shM[TPB], shLen[TPB];
  const int t = threadIdx.x;
  preamble(lens, shC, shM, shLen, t);
  const int K  = shC[BB - 1];
  const int ml = shM[0];

  const int gid = blockIdx.x * TPB + t;
  const size_t Nz = (size_t)NN;

  // ---- candidate-indexed outputs at flat f = gid ----
  {
    int f   = gid;
    int row = f / LLW;
    int jj  = f - row * LLW;
    int b2  = row >> 9;        // row / SS
    int s2  = row & (SS - 1);  // row % SS
    int e2  = s2 + jj;
    out[f]           = (e2 < shLen[b2]) ? 1.0f : 0.0f;  // viable
    out[26 * Nz + f] = (float)s2;        // start_candidates
    out[27 * Nz + f] = (float)e2;        // end_candidates
    out[28 * Nz + f] = (float)(jj + 1);  // len_candidates
  }
  // ---- compacted-indexed outputs at k = gid ----
  {
    int k = gid, b, s, j;
    invert(k, shC, shLen, K, &b, &s, &j);
    out[Nz      + k] = (float)b;          // viable_batch_indices
    out[2 * Nz  + k] = (float)s;          // viable_starts
    out[3 * Nz  + k] = (float)(s + j);    // viable_ends
    out[4 * Nz  + k] = (float)(j + 1);    // viable_lengths
    out[25 * Nz + k] = pw[((size_t)b * SS + s) * LLW + j];  // viable_p_weights
    // unit-id row: 20 f32 = 5 float4, base byte offset 80*k -> 16B aligned
    const int* srow = seqs + (size_t)b * SS;
    float4* urow = (float4*)(out + 5 * Nz + (size_t)k * LLW);
    int ml1 = ml - 1;
#pragma unroll
    for (int i = 0; i < LLW / 4; i++) {
      int p0 = s + 4 * i;     if (p0 > ml1) p0 = ml1;
      int p1 = s + 4 * i + 1; if (p1 > ml1) p1 = ml1;
      int p2 = s + 4 * i + 2; if (p2 > ml1) p2 = ml1;
      int p3 = s + 4 * i + 3; if (p3 > ml1) p3 = ml1;
      float4 v;
      v.x = (float)srow[p0];
      v.y = (float)srow[p1];
      v.z = (float)srow[p2];
      v.w = (float)srow[p3];
      urow[i] = v;
    }
  }
}

extern "C" void kernel_launch(void* const* d_in, const int* in_sizes, int n_in,
                              void* d_out, int out_size, void* d_ws, size_t ws_size,
                              hipStream_t stream) {
  const int*   seqs = (const int*)d_in[0];    // lost_unit_id_seqs [128,512]
  const int*   lens = (const int*)d_in[1];    // lost_lengths [128]
  const float* pw   = (const float*)d_in[2];  // p_weights [128,512,20]
  float* out = (float*)d_out;

  span_full<<<NN / TPB, TPB, 0, stream>>>(seqs, lens, pw, out);
}

// Round 7
// 165.934 us; speedup vs baseline: 1.0415x; 1.0415x over previous
//
#include <hip/hip_runtime.h>
#include <stdint.h>

#define TPB 256
#define BB  128
#define SS  512
#define LLW 20
#define NN  (BB * SS * LLW)   // 1,310,720

// lens -> LDS, inclusive prefix of per-batch viable counts
// (count(b) = L*len_b - L(L-1)/2, len>=L guaranteed), max(lens).
static __device__ __forceinline__ void preamble(const int* __restrict__ lens,
                                                int* shC, int* shM, int* shLen,
                                                int t) {
  int len0 = (t < BB) ? lens[t] : 0;
  shLen[t] = len0;
  shC[t] = (t < BB) ? (LLW * len0 - (LLW * (LLW - 1)) / 2) : 0;
  shM[t] = len0;
  for (int off = 1; off < TPB; off <<= 1) {
    __syncthreads();
    int aC = shC[t]; int bC = (t >= off) ? shC[t - off] : 0;
    int aM = shM[t]; int bM = shM[t ^ off];
    __syncthreads();
    shC[t] = aC + bC;
    shM[t] = (aM > bM) ? aM : bM;
  }
  __syncthreads();
}

// Invert compacted index k -> (b, s, j). k >= K gives pad (0,0,0).
static __device__ __forceinline__ void invert(int k, const int* shC,
                                              const int* shLen, int K,
                                              int* pb, int* ps, int* pj) {
  int b = 0, s = 0, j = 0;
  if (k < K) {
    int lo = 0, hi = BB - 1;
    while (lo < hi) {            // smallest b with inclusive count > k
      int mid = (lo + hi) >> 1;
      if (shC[mid] > k) hi = mid; else lo = mid + 1;
    }
    b = lo;
    int base = (b == 0) ? 0 : shC[b - 1];
    int m    = k - base;
    int lenb = shLen[b];
    int full = LLW * (lenb - LLW + 1);   // rows with all L spans viable
    if (m < full) {
      s = m / LLW;
      j = m - s * LLW;
    } else {                             // triangular tail; row s has len_b - s spans
      int Cb = shC[b] - base;
      int tt = Cb - m;                   // in (r(r-1)/2, r(r+1)/2], r = lenb - s
      float rf = (sqrtf(8.0f * (float)tt + 1.0f) - 1.0f) * 0.5f;
      int r = (int)(rf + 0.5f);
      if (r * (r + 1) / 2 < tt) r++;
      if (r > 1 && r * (r - 1) / 2 >= tt) r--;
      s = lenb - r;
      j = r * (r + 1) / 2 - tt;
    }
  }
  *pb = b; *ps = s; *pj = j;
}

// d_out is FLOAT32. Return-order layout, offsets in units of NN:
//   0 viable | 1 batch | 2 starts | 3 ends | 4 lengths | 5..24 units
//   25 p_weights | 26 start_cand | 27 end_cand | 28 len_cand
__global__ __launch_bounds__(TPB) void span_full(
    const int* __restrict__ seqs,    // [B*S] int32
    const int* __restrict__ lens,    // [B] int32
    const float* __restrict__ pw,    // [B*S*L] f32
    float* __restrict__ out) {
  __shared__ int shC[TPB], shM[TPB], shLen[TPB];
  __shared__ int sBS[TPB];           // packed (b<<16)|s per local k
  const int t = threadIdx.x;
  preamble(lens, shC, shM, shLen, t);
  const int K  = shC[BB - 1];
  const int ml = shM[0];

  const int gid = blockIdx.x * TPB + t;
  const size_t Nz = (size_t)NN;

  // ---- phase 1a: candidate-indexed outputs at flat f = gid (coalesced dwords)
  {
    int f   = gid;
    int row = f / LLW;
    int jj  = f - row * LLW;
    int b2  = row >> 9;        // row / SS
    int s2  = row & (SS - 1);  // row % SS
    int e2  = s2 + jj;
    out[f]           = (e2 < shLen[b2]) ? 1.0f : 0.0f;  // viable
    out[26 * Nz + f] = (float)s2;        // start_candidates
    out[27 * Nz + f] = (float)e2;        // end_candidates
    out[28 * Nz + f] = (float)(jj + 1);  // len_candidates
  }
  // ---- phase 1b: compacted-indexed scalars at k = gid (coalesced dwords)
  {
    int k = gid, b, s, j;
    invert(k, shC, shLen, K, &b, &s, &j);
    out[Nz      + k] = (float)b;          // viable_batch_indices
    out[2 * Nz  + k] = (float)s;          // viable_starts
    out[3 * Nz  + k] = (float)(s + j);    // viable_ends
    out[4 * Nz  + k] = (float)(j + 1);    // viable_lengths
    out[25 * Nz + k] = pw[((size_t)b * SS + s) * LLW + j];  // viable_p_weights
    sBS[t] = (b << 16) | s;               // hand (b,s) to phase 2
  }
  __syncthreads();
  // ---- phase 2: units region, fully coalesced float4 stores.
  // Block's span = TPB rows x 20 floats = 1280 float4 chunks; rows are exactly
  // 5 chunks so a chunk never straddles rows. Re-gather seqs (L2-resident).
  {
    int ml1 = ml - 1;
    float4* udst = (float4*)(out + 5 * Nz + (size_t)blockIdx.x * (TPB * LLW));
#pragma unroll
    for (int c = 0; c < LLW / 4; c++) {
      int chunk = t + c * TPB;           // 0..1279, lane-consecutive
      int krow  = chunk / 5;             // local k
      int e0    = (chunk - krow * 5) * 4;
      int bs    = sBS[krow];             // 5-lane broadcast groups
      const int* srow = seqs + ((size_t)(bs >> 16) << 9);
      int s = bs & 0xFFFF;
      int p0 = s + e0;     if (p0 > ml1) p0 = ml1;
      int p1 = s + e0 + 1; if (p1 > ml1) p1 = ml1;
      int p2 = s + e0 + 2; if (p2 > ml1) p2 = ml1;
      int p3 = s + e0 + 3; if (p3 > ml1) p3 = ml1;
      float4 v;
      v.x = (float)srow[p0];
      v.y = (float)srow[p1];
      v.z = (float)srow[p2];
      v.w = (float)srow[p3];
      udst[chunk] = v;
    }
  }
}

extern "C" void kernel_launch(void* const* d_in, const int* in_sizes, int n_in,
                              void* d_out, int out_size, void* d_ws, size_t ws_size,
                              hipStream_t stream) {
  const int*   seqs = (const int*)d_in[0];    // lost_unit_id_seqs [128,512]
  const int*   lens = (const int*)d_in[1];    // lost_lengths [128]
  const float* pw   = (const float*)d_in[2];  // p_weights [128,512,20]
  float* out = (float*)d_out;

  span_full<<<NN / TPB, TPB, 0, stream>>>(seqs, lens, pw, out);
}

// Round 8
// 161.714 us; speedup vs baseline: 1.0687x; 1.0261x over previous
//
#include <hip/hip_runtime.h>
#include <stdint.h>

#define TPB 256
#define BB  128
#define SS  512
#define LLW 20
#define NN  (BB * SS * LLW)   // 1,310,720
#define KPT 4                 // k's per thread
#define KPB (TPB * KPT)       // 1024 k's per block
#define MAXROWS 8             // staged seqs rows (proven bound: 6)
#define RSTRIDE 516           // LDS row stride (ints): 16B-aligned, bank-staggered

// lens -> LDS, inclusive prefix of per-batch viable counts
// (count(b) = L*len_b - L(L-1)/2, len>=L guaranteed), max(lens).
static __device__ __forceinline__ void preamble(const int* __restrict__ lens,
                                                int* shC, int* shM, int* shLen,
                                                int t) {
  int len0 = (t < BB) ? lens[t] : 0;
  shLen[t] = len0;
  shC[t] = (t < BB) ? (LLW * len0 - (LLW * (LLW - 1)) / 2) : 0;
  shM[t] = len0;
  for (int off = 1; off < TPB; off <<= 1) {
    __syncthreads();
    int aC = shC[t]; int bC = (t >= off) ? shC[t - off] : 0;
    int aM = shM[t]; int bM = shM[t ^ off];
    __syncthreads();
    shC[t] = aC + bC;
    shM[t] = (aM > bM) ? aM : bM;
  }
  __syncthreads();
}

static __device__ __forceinline__ int batch_of(int k, const int* shC) {
  int lo = 0, hi = BB - 1;
  while (lo < hi) {            // smallest b with inclusive count > k
    int mid = (lo + hi) >> 1;
    if (shC[mid] > k) hi = mid; else lo = mid + 1;
  }
  return lo;
}

// Invert compacted index k -> (b, s, j). k >= K gives pad (0,0,0).
static __device__ __forceinline__ void invert(int k, const int* shC,
                                              const int* shLen, int K,
                                              int* pb, int* ps, int* pj) {
  int b = 0, s = 0, j = 0;
  if (k < K) {
    b = batch_of(k, shC);
    int base = (b == 0) ? 0 : shC[b - 1];
    int m    = k - base;
    int lenb = shLen[b];
    int full = LLW * (lenb - LLW + 1);   // rows with all L spans viable
    if (m < full) {
      s = m / LLW;
      j = m - s * LLW;
    } else {                             // triangular tail; row s has len_b - s spans
      int Cb = shC[b] - base;
      int tt = Cb - m;                   // in (r(r-1)/2, r(r+1)/2], r = lenb - s
      float rf = (sqrtf(8.0f * (float)tt + 1.0f) - 1.0f) * 0.5f;
      int r = (int)(rf + 0.5f);
      if (r * (r + 1) / 2 < tt) r++;
      if (r > 1 && r * (r - 1) / 2 >= tt) r--;
      s = lenb - r;
      j = r * (r + 1) / 2 - tt;
    }
  }
  *pb = b; *ps = s; *pj = j;
}

// d_out is FLOAT32. Return-order layout, offsets in units of NN:
//   0 viable | 1 batch | 2 starts | 3 ends | 4 lengths | 5..24 units
//   25 p_weights | 26 start_cand | 27 end_cand | 28 len_cand
__global__ __launch_bounds__(TPB) void span_full(
    const int* __restrict__ seqs,    // [B*S] int32
    const int* __restrict__ lens,    // [B] int32
    const float* __restrict__ pw,    // [B*S*L] f32
    float* __restrict__ out) {
  __shared__ int shC[TPB], shM[TPB], shLen[TPB];
  __shared__ int sBS[KPB];                 // packed (b<<16)|s per local k
  __shared__ int sRows[MAXROWS * RSTRIDE]; // staged seqs rows
  const int t = threadIdx.x;
  preamble(lens, shC, shM, shLen, t);
  const int K  = shC[BB - 1];
  const int ml = shM[0];

  const int gid    = blockIdx.x * TPB + t;
  const int k0     = gid * KPT;            // this thread's first k / f
  const int blk_k0 = blockIdx.x * KPB;
  const size_t Nz  = (size_t)NN;

  // ---- stage this block's seqs window into LDS (coalesced int4 loads) ----
  int kq0 = blk_k0;           if (kq0 > K - 1) kq0 = K - 1;
  int kq1 = blk_k0 + KPB - 1; if (kq1 > K - 1) kq1 = K - 1;
  const int bf = batch_of(kq0, shC);
  int nrows = (blk_k0 < K) ? (batch_of(kq1, shC) - bf + 1) : 0;
  if (nrows > MAXROWS) nrows = MAXROWS;    // defensive; bound proof says <= 6
  {
    const int4* src = (const int4*)(seqs + (size_t)bf * SS);
    for (int q = t; q < nrows * (SS / 4); q += TPB) {
      int lin = q << 2;
      int r = lin >> 9, p = lin & (SS - 1);
      *(int4*)(sRows + r * RSTRIDE + p) = src[q];
    }
  }

  // ---- phase 1a: candidate-indexed outputs, 4 consecutive f, float4 stores --
  {
    float qv[KPT], qsc[KPT], qec[KPT], qlc[KPT];
#pragma unroll
    for (int i = 0; i < KPT; i++) {
      int f   = k0 + i;
      int row = f / LLW;
      int jj  = f - row * LLW;
      int b2  = row >> 9;        // row / SS
      int s2  = row & (SS - 1);  // row % SS
      int e2  = s2 + jj;
      qv[i]  = (e2 < shLen[b2]) ? 1.0f : 0.0f;
      qsc[i] = (float)s2; qec[i] = (float)e2; qlc[i] = (float)(jj + 1);
    }
    *(float4*)(out + k0)           = make_float4(qv[0], qv[1], qv[2], qv[3]);
    *(float4*)(out + 26 * Nz + k0) = make_float4(qsc[0], qsc[1], qsc[2], qsc[3]);
    *(float4*)(out + 27 * Nz + k0) = make_float4(qec[0], qec[1], qec[2], qec[3]);
    *(float4*)(out + 28 * Nz + k0) = make_float4(qlc[0], qlc[1], qlc[2], qlc[3]);
  }
  // ---- phase 1b: compacted scalars, invert once + incremental stepping ----
  {
    int b, s, j;
    invert(k0, shC, shLen, K, &b, &s, &j);
    float qb[KPT], qs[KPT], qe[KPT], ql[KPT], qp[KPT];
#pragma unroll
    for (int i = 0; i < KPT; i++) {
      int ki = k0 + i;
      int vb = 0, vs = 0, vj = 0;
      if (ki < K) {
        vb = b; vs = s; vj = j;
        j++;                                  // advance to next k
        int lenb = shLen[b];
        int cs = lenb - s; if (cs > LLW) cs = LLW;
        if (j >= cs) { j = 0; s++; if (s >= lenb) { s = 0; b++; } }
      }
      qb[i] = (float)vb; qs[i] = (float)vs;
      qe[i] = (float)(vs + vj); ql[i] = (float)(vj + 1);
      qp[i] = pw[((size_t)vb * SS + vs) * LLW + vj];
      sBS[t * KPT + i] = (vb << 16) | vs;
    }
    *(float4*)(out + Nz + k0)      = make_float4(qb[0], qb[1], qb[2], qb[3]);
    *(float4*)(out + 2 * Nz + k0)  = make_float4(qs[0], qs[1], qs[2], qs[3]);
    *(float4*)(out + 3 * Nz + k0)  = make_float4(qe[0], qe[1], qe[2], qe[3]);
    *(float4*)(out + 4 * Nz + k0)  = make_float4(ql[0], ql[1], ql[2], ql[3]);
    *(float4*)(out + 25 * Nz + k0) = make_float4(qp[0], qp[1], qp[2], qp[3]);
  }
  __syncthreads();
  // ---- phase 2: units region from LDS, lane-consecutive float4 stores ----
  // Block span = 1024 rows x 20 floats = 5120 float4 chunks (80 KB contiguous).
  {
    int ml1 = ml - 1;
    float4* udst = (float4*)(out + 5 * Nz + (size_t)blk_k0 * LLW);
    for (int c = 0; c < (KPB * (LLW / 4)) / TPB; c++) {   // 20 iterations
      int chunk = t + c * TPB;
      int krow  = chunk / 5;
      int e0    = (chunk - krow * 5) << 2;
      int bs    = sBS[krow];
      int b = bs >> 16, s = bs & 0xFFFF;
      int p0 = s + e0;     if (p0 > ml1) p0 = ml1;
      int p1 = s + e0 + 1; if (p1 > ml1) p1 = ml1;
      int p2 = s + e0 + 2; if (p2 > ml1) p2 = ml1;
      int p3 = s + e0 + 3; if (p3 > ml1) p3 = ml1;
      float4 v;
      int ridx = b - bf;
      if ((unsigned)ridx < (unsigned)nrows) {     // staged row (common case)
        const int* rp = sRows + ridx * RSTRIDE;
        v.x = (float)rp[p0]; v.y = (float)rp[p1];
        v.z = (float)rp[p2]; v.w = (float)rp[p3];
      } else {                                    // pad / out-of-window row
        const int* rp = seqs + (size_t)b * SS;
        v.x = (float)rp[p0]; v.y = (float)rp[p1];
        v.z = (float)rp[p2]; v.w = (float)rp[p3];
      }
      udst[chunk] = v;
    }
  }
}

extern "C" void kernel_launch(void* const* d_in, const int* in_sizes, int n_in,
                              void* d_out, int out_size, void* d_ws, size_t ws_size,
                              hipStream_t stream) {
  const int*   seqs = (const int*)d_in[0];    // lost_unit_id_seqs [128,512]
  const int*   lens = (const int*)d_in[1];    // lost_lengths [128]
  const float* pw   = (const float*)d_in[2];  // p_weights [128,512,20]
  float* out = (float*)d_out;

  span_full<<<NN / KPB, TPB, 0, stream>>>(seqs, lens, pw, out);  // 1280 blocks
}